// Round 12
// baseline (419.006 us; speedup 1.0000x reference)
//
#include <hip/hip_runtime.h>

#define T_STEPS 500
#define BATCH   4096

typedef float f32x4 __attribute__((ext_vector_type(4)));
typedef float f32x2 __attribute__((ext_vector_type(2)));
typedef short s16x8 __attribute__((ext_vector_type(8)));

__device__ __forceinline__ unsigned short bf16_rne(float f) {
    union { float f; unsigned u; } c; c.f = f;
    unsigned u = c.u;
    return (unsigned short)((u + 0x7FFFu + ((u >> 16) & 1u)) >> 16);
}
__device__ __forceinline__ float bf16_tof(unsigned short h) {
    union { unsigned u; float f; } c; c.u = ((unsigned)h) << 16;
    return c.f;
}

// ---- packed f32 (VOP3P) helpers ----
__device__ __forceinline__ f32x2 pk_mul(f32x2 a, f32x2 b) {
    f32x2 d;
    asm("v_pk_mul_f32 %0, %1, %2" : "=v"(d) : "v"(a), "v"(b));
    return d;
}
__device__ __forceinline__ f32x2 pk_fma(f32x2 a, f32x2 b, f32x2 c) {
    f32x2 d;
    asm("v_pk_fma_f32 %0, %1, %2, %3" : "=v"(d) : "v"(a), "v"(b), "v"(c));
    return d;
}

// B-frag [v|v]: duplicated into both K-16 halves (for compensated K=16 ops)
__device__ __forceinline__ s16x8 make_hi(f32x4 v) {
    unsigned p01, p23;
    asm("v_cvt_pk_bf16_f32 %0, %1, %2" : "=v"(p01) : "v"(v[0]), "v"(v[1]));
    asm("v_cvt_pk_bf16_f32 %0, %1, %2" : "=v"(p23) : "v"(v[2]), "v"(v[3]));
    union { unsigned u[4]; s16x8 s; } r;
    r.u[0] = p01; r.u[1] = p23; r.u[2] = p01; r.u[3] = p23;
    return r.s;
}

// B-frag [a|b] from two f32x4 (plain K=32 ops)
__device__ __forceinline__ s16x8 pack2(f32x4 a, f32x4 b) {
    unsigned p01, p23, q01, q23;
    asm("v_cvt_pk_bf16_f32 %0, %1, %2" : "=v"(p01) : "v"(a[0]), "v"(a[1]));
    asm("v_cvt_pk_bf16_f32 %0, %1, %2" : "=v"(p23) : "v"(a[2]), "v"(a[3]));
    asm("v_cvt_pk_bf16_f32 %0, %1, %2" : "=v"(q01) : "v"(b[0]), "v"(b[1]));
    asm("v_cvt_pk_bf16_f32 %0, %1, %2" : "=v"(q23) : "v"(b[2]), "v"(b[3]));
    union { unsigned u[4]; s16x8 s; } r;
    r.u[0] = p01; r.u[1] = p23; r.u[2] = q01; r.u[3] = q23;
    return r.s;
}

// B-frag [a|b] from four f32x2 pairs (plain K=32 ops)
__device__ __forceinline__ s16x8 pack2p(f32x2 a0, f32x2 a1, f32x2 b0, f32x2 b1) {
    unsigned p01, p23, q01, q23;
    asm("v_cvt_pk_bf16_f32 %0, %1, %2" : "=v"(p01) : "v"(a0[0]), "v"(a0[1]));
    asm("v_cvt_pk_bf16_f32 %0, %1, %2" : "=v"(p23) : "v"(a1[0]), "v"(a1[1]));
    asm("v_cvt_pk_bf16_f32 %0, %1, %2" : "=v"(q01) : "v"(b0[0]), "v"(b0[1]));
    asm("v_cvt_pk_bf16_f32 %0, %1, %2" : "=v"(q23) : "v"(b1[0]), "v"(b1[1]));
    union { unsigned u[4]; s16x8 s; } r;
    r.u[0] = p01; r.u[1] = p23; r.u[2] = q01; r.u[3] = q23;
    return r.s;
}

// Compensated A-frag [Whi|Wlo] over one K-16 chunk (use with B=[a|a]).
__device__ __forceinline__ s16x8 load_pair(const float* __restrict__ W, int ld,
                                           int m0, int k0, int M, int K, int lane) {
    const int m = m0 + (lane & 15);
    const int g = lane >> 4;
    s16x8 r;
    #pragma unroll
    for (int j = 0; j < 4; ++j) {
        const int k = k0 + 4 * g + j;
        const float w = (m < M && k < K) ? W[m * ld + k] : 0.0f;
        const unsigned short hi = bf16_rne(w);
        const unsigned short lo = bf16_rne(w - bf16_tof(hi));
        r[j]     = (short)hi;
        r[j + 4] = (short)lo;
    }
    return r;
}

// Plain bf16 A-frag over a K-32 window (use with pack2/pack2p B-frags).
__device__ __forceinline__ s16x8 load_plain32(const float* __restrict__ W, int ld,
                                              int m0, int k0, int M, int K, int lane) {
    const int m = m0 + (lane & 15);
    const int g = lane >> 4;
    s16x8 r;
    #pragma unroll
    for (int j = 0; j < 8; ++j) {
        const int k = k0 + ((j < 4) ? (4 * g + j) : (16 + 4 * g + (j - 4)));
        const float w = (m < M && k < K) ? W[m * ld + k] : 0.0f;
        r[j] = (short)bf16_rne(w);
    }
    return r;
}

// GRU gates: wide-range, trans-based.
__device__ __forceinline__ float fast_tanh(float x) {
    float e = __builtin_amdgcn_exp2f(2.8853900817779268f * x);
    return fmaf(-2.0f, __builtin_amdgcn_rcpf(e + 1.0f), 1.0f);
}
__device__ __forceinline__ float fast_sigmoid(float x) {
    float e = __builtin_amdgcn_exp2f(-1.4426950408889634f * x);
    return __builtin_amdgcn_rcpf(1.0f + e);
}

#define MFMA(a, b, c) __builtin_amdgcn_mfma_f32_16x16x32_bf16((a), (b), (c), 0, 0, 0)

__global__ __launch_bounds__(64) void odernn_mfma(
    const float* __restrict__ x,    // [T, B, 32]
    const float* __restrict__ t,    // [T]
    const float* __restrict__ W1, const float* __restrict__ b1,   // [50,16],[50]
    const float* __restrict__ W2, const float* __restrict__ b2,   // [16,50],[16]
    const float* __restrict__ Wih, const float* __restrict__ bih, // [48,32],[48]
    const float* __restrict__ Whh, const float* __restrict__ bhh, // [48,16],[48]
    const float* __restrict__ Wout, const float* __restrict__ bout,
    float* __restrict__ out)        // [T-1, B, 1]
{
    const int lane  = threadIdx.x;
    const int g     = lane >> 4;
    const int col   = lane & 15;
    const int ebase = blockIdx.x * 16;

    // ---- weight A-frags ----
    s16x8 W1A[4], W2P[2], WihP[3], WhhA[3], WoutA;
    #pragma unroll
    for (int c = 0; c < 4; ++c) W1A[c] = load_pair(W1, 16, 16 * c, 0, 50, 16, lane);
    #pragma unroll
    for (int c = 0; c < 2; ++c) W2P[c] = load_plain32(W2, 50, 0, 32 * c, 16, 50, lane);
    #pragma unroll
    for (int m = 0; m < 3; ++m) WihP[m] = load_plain32(Wih, 32, 16 * m, 0, 48, 32, lane);
    #pragma unroll
    for (int m = 0; m < 3; ++m) WhhA[m] = load_pair(Whh, 16, 16 * m, 0, 48, 16, lane);
    WoutA = load_pair(Wout, 16, 0, 0, 1, 16, lane);   // row 0 only

    // ---- bias C-frags (f32, row = 4g + i within tile) ----
    f32x4 b1f[4], brzf[2], b2f, bxnf, bhnf, boutC;
    #pragma unroll
    for (int c = 0; c < 4; ++c)
        #pragma unroll
        for (int i = 0; i < 4; ++i) {
            int rr = 16 * c + 4 * g + i;
            b1f[c][i] = (rr < 50) ? b1[rr] : 0.0f;
        }
    #pragma unroll
    for (int i = 0; i < 4; ++i) {
        b2f[i]  = b2[4 * g + i];
        brzf[0][i] = bih[4 * g + i]      + bhh[4 * g + i];
        brzf[1][i] = bih[16 + 4 * g + i] + bhh[16 + 4 * g + i];
        bxnf[i] = bih[32 + 4 * g + i];
        bhnf[i] = bhh[32 + 4 * g + i];
        boutC[i] = 0.0f;
    }
    if (g == 0) boutC[0] = bout[0];

    // packed poly_tanh constants (odd deg-7 fit on [0,1.5], poly(0)==0)
    const f32x2 C3 = {-0.0136472f, -0.0136472f};
    const f32x2 C2 = { 0.0941244f,  0.0941244f};
    const f32x2 C1 = {-0.3183021f, -0.3183021f};
    const f32x2 C0 = { 0.9985576f,  0.9985576f};
    // poly2: 5 packed ops for 2 values
    auto poly2 = [&](f32x2 xx) -> f32x2 {
        f32x2 u = pk_mul(xx, xx);
        f32x2 p = pk_fma(u, C3, C2);
        p = pk_fma(u, p, C1);
        p = pk_fma(u, p, C0);
        return pk_mul(xx, p);
    };
    auto lo2 = [](f32x4 v) -> f32x2 { f32x2 r; r[0] = v[0]; r[1] = v[1]; return r; };
    auto hi2 = [](f32x4 v) -> f32x2 { f32x2 r; r[0] = v[2]; r[1] = v[3]; return r; };

    // ---- state ----
    f32x4 h = {0.0f, 0.0f, 0.0f, 0.0f};
    s16x8 hb = make_hi(h);                 // carried bf16 frag of h

    // ---- pipelined x / rotated x-side GRU MFMAs ----
    const float* xbase = x + ((size_t)(ebase + col) << 5) + 4 * g;
    f32x4 xa_n = *(const f32x4*)(xbase);
    f32x4 xb_n = *(const f32x4*)(xbase + 16);
    s16x8 xB = pack2(xa_n, xb_n);
    f32x4 gr_x = MFMA(WihP[0], xB, brzf[0]);   // step-0 x-side gates
    f32x4 gz_x = MFMA(WihP[1], xB, brzf[1]);
    f32x4 gxn  = MFMA(WihP[2], xB, bxnf);

    float tcur = t[0];
    float tn   = t[1];

    #pragma unroll 2
    for (int ti = 0; ti < T_STEPS - 1; ++ti) {
        // prefetch next x early (consumed at the tail of this iteration)
        const float* xnxt = xbase + ((size_t)(ti + 1) * BATCH << 5);
        xa_n = *(const f32x4*)(xnxt);
        xb_n = *(const f32x4*)(xnxt + 16);
        const int ti2 = (ti + 2 < T_STEPS) ? (ti + 2) : (T_STEPS - 1);
        const float tnn = t[ti2];

        const float dt = tn - tcur;
        tcur = tn;
        tn = tnn;

        // ---- ODE: forward Euler over the full interval.
        // LTE = dt^2/2*|Jf| ~ 1.5e-5/step; GRU contraction -> ~4e-5 total.
        f32x4 y0 = MFMA(W1A[0], hb, b1f[0]);
        f32x4 y1 = MFMA(W1A[1], hb, b1f[1]);
        f32x4 y2 = MFMA(W1A[2], hb, b1f[2]);
        f32x4 y3 = MFMA(W1A[3], hb, b1f[3]);   // rows 50-63: zero W,b -> poly(0)=0
        f32x2 t00 = poly2(lo2(y0)), t01 = poly2(hi2(y0));
        f32x2 t10 = poly2(lo2(y1)), t11 = poly2(hi2(y1));
        f32x2 t20 = poly2(lo2(y2)), t21 = poly2(hi2(y2));
        f32x2 t30 = poly2(lo2(y3)), t31 = poly2(hi2(y3));
        f32x4 f = MFMA(W2P[0], pack2p(t00, t01, t10, t11), b2f);
        f = MFMA(W2P[1], pack2p(t20, t21, t30, t31), f);
        h += dt * f;

        // ---- GRU h-side: 3 MFMAs on the post-ODE critical path ----
        const s16x8 hh = make_hi(h);
        const f32x4 gr = MFMA(WhhA[0], hh, gr_x);
        const f32x4 gz = MFMA(WhhA[1], hh, gz_x);
        const f32x4 ghn = MFMA(WhhA[2], hh, bhnf);

        f32x4 hnew;
        #pragma unroll
        for (int i = 0; i < 4; ++i) {
            const float r = fast_sigmoid(gr[i]);
            const float z = fast_sigmoid(gz[i]);
            const float n = fast_tanh(gxn[i] + r * ghn[i]);
            hnew[i] = n + z * (h[i] - n);
        }
        h = hnew;

        // ---- tail: next step's x-side MFMAs overlap the trans/store tail ----
        xB = pack2(xa_n, xb_n);
        gr_x = MFMA(WihP[0], xB, brzf[0]);
        gz_x = MFMA(WihP[1], xB, brzf[1]);

        hb = make_hi(h);
        f32x4 od = MFMA(WoutA, hb, boutC);
        gxn = MFMA(WihP[2], xB, bxnf);
        if (lane < 16) out[(size_t)ti * BATCH + ebase + lane] = od[0];
    }
}

extern "C" void kernel_launch(void* const* d_in, const int* in_sizes, int n_in,
                              void* d_out, int out_size, void* d_ws, size_t ws_size,
                              hipStream_t stream) {
    const float* x    = (const float*)d_in[0];
    const float* t    = (const float*)d_in[1];
    const float* W1   = (const float*)d_in[2];
    const float* b1   = (const float*)d_in[3];
    const float* W2   = (const float*)d_in[4];
    const float* b2   = (const float*)d_in[5];
    const float* Wih  = (const float*)d_in[6];
    const float* bih  = (const float*)d_in[7];
    const float* Whh  = (const float*)d_in[8];
    const float* bhh  = (const float*)d_in[9];
    const float* Wout = (const float*)d_in[10];
    const float* bout = (const float*)d_in[11];
    float* out = (float*)d_out;

    dim3 grid(BATCH / 16), block(64);
    hipLaunchKernelGGL(odernn_mfma, grid, block, 0, stream,
                       x, t, W1, b1, W2, b2, Wih, bih, Whh, bhh, Wout, bout, out);
}

// Round 14
// 395.423 us; speedup vs baseline: 1.0596x; 1.0596x over previous
//
#include <hip/hip_runtime.h>

#define T_STEPS 500
#define BATCH   4096

typedef float f32x4 __attribute__((ext_vector_type(4)));
typedef short s16x8 __attribute__((ext_vector_type(8)));

__device__ __forceinline__ unsigned short bf16_rne(float f) {
    union { float f; unsigned u; } c; c.f = f;
    unsigned u = c.u;
    return (unsigned short)((u + 0x7FFFu + ((u >> 16) & 1u)) >> 16);
}
__device__ __forceinline__ float bf16_tof(unsigned short h) {
    union { unsigned u; float f; } c; c.u = ((unsigned)h) << 16;
    return c.f;
}

// B-frag [v|v]: duplicated into both K-16 halves (for compensated K=16 ops)
__device__ __forceinline__ s16x8 make_hi(f32x4 v) {
    unsigned p01, p23;
    asm("v_cvt_pk_bf16_f32 %0, %1, %2" : "=v"(p01) : "v"(v[0]), "v"(v[1]));
    asm("v_cvt_pk_bf16_f32 %0, %1, %2" : "=v"(p23) : "v"(v[2]), "v"(v[3]));
    union { unsigned u[4]; s16x8 s; } r;
    r.u[0] = p01; r.u[1] = p23; r.u[2] = p01; r.u[3] = p23;
    return r.s;
}

// B-frag [a|b]: two different 16-wide K-halves (plain K=32 ops)
__device__ __forceinline__ s16x8 pack2(f32x4 a, f32x4 b) {
    unsigned p01, p23, q01, q23;
    asm("v_cvt_pk_bf16_f32 %0, %1, %2" : "=v"(p01) : "v"(a[0]), "v"(a[1]));
    asm("v_cvt_pk_bf16_f32 %0, %1, %2" : "=v"(p23) : "v"(a[2]), "v"(a[3]));
    asm("v_cvt_pk_bf16_f32 %0, %1, %2" : "=v"(q01) : "v"(b[0]), "v"(b[1]));
    asm("v_cvt_pk_bf16_f32 %0, %1, %2" : "=v"(q23) : "v"(b[2]), "v"(b[3]));
    union { unsigned u[4]; s16x8 s; } r;
    r.u[0] = p01; r.u[1] = p23; r.u[2] = q01; r.u[3] = q23;
    return r.s;
}

// Compensated A-frag [Whi|Wlo] over one K-16 chunk (use with B=[a|a]).
__device__ __forceinline__ s16x8 load_pair(const float* __restrict__ W, int ld,
                                           int m0, int k0, int M, int K, int lane) {
    const int m = m0 + (lane & 15);
    const int g = lane >> 4;
    s16x8 r;
    #pragma unroll
    for (int j = 0; j < 4; ++j) {
        const int k = k0 + 4 * g + j;
        const float w = (m < M && k < K) ? W[m * ld + k] : 0.0f;
        const unsigned short hi = bf16_rne(w);
        const unsigned short lo = bf16_rne(w - bf16_tof(hi));
        r[j]     = (short)hi;
        r[j + 4] = (short)lo;
    }
    return r;
}

// Plain bf16 A-frag over a K-32 window (use with pack2 B-frags).
__device__ __forceinline__ s16x8 load_plain32(const float* __restrict__ W, int ld,
                                              int m0, int k0, int M, int K, int lane) {
    const int m = m0 + (lane & 15);
    const int g = lane >> 4;
    s16x8 r;
    #pragma unroll
    for (int j = 0; j < 8; ++j) {
        const int k = k0 + ((j < 4) ? (4 * g + j) : (16 + 4 * g + (j - 4)));
        const float w = (m < M && k < K) ? W[m * ld + k] : 0.0f;
        r[j] = (short)bf16_rne(w);
    }
    return r;
}

// ODE tanh: odd deg-7 fit on [0,1.5] (|err|<9e-4; dt-scaled in h). poly(0)==0.
__device__ __forceinline__ float poly_tanh(float x) {
    const float u = x * x;
    float p = fmaf(u, -0.0136472f, 0.0941244f);
    p = fmaf(u, p, -0.3183021f);
    p = fmaf(u, p, 0.9985576f);
    return x * p;
}

// GRU gates: wide-range, trans-based.
__device__ __forceinline__ float fast_tanh(float x) {
    float e = __builtin_amdgcn_exp2f(2.8853900817779268f * x);
    return fmaf(-2.0f, __builtin_amdgcn_rcpf(e + 1.0f), 1.0f);
}
__device__ __forceinline__ float fast_sigmoid(float x) {
    float e = __builtin_amdgcn_exp2f(-1.4426950408889634f * x);
    return __builtin_amdgcn_rcpf(1.0f + e);
}

#define MFMA(a, b, c) __builtin_amdgcn_mfma_f32_16x16x32_bf16((a), (b), (c), 0, 0, 0)

__global__ __launch_bounds__(128) void odernn_mfma2(
    const float* __restrict__ x,    // [T, B, 32]
    const float* __restrict__ t,    // [T]
    const float* __restrict__ W1, const float* __restrict__ b1,   // [50,16],[50]
    const float* __restrict__ W2, const float* __restrict__ b2,   // [16,50],[16]
    const float* __restrict__ Wih, const float* __restrict__ bih, // [48,32],[48]
    const float* __restrict__ Whh, const float* __restrict__ bhh, // [48,16],[48]
    const float* __restrict__ Wout, const float* __restrict__ bout,
    float* __restrict__ out)        // [T-1, B, 1]
{
    const int tid   = threadIdx.x;
    const int w     = tid >> 6;          // wave 0 / wave 1
    const int lane  = tid & 63;
    const int g     = lane >> 4;
    const int col   = lane & 15;
    const int ebase = blockIdx.x * 16;

    // LDS exchange buffers.
    // f-region: writes in (bar2(ti-1), bar1(ti)); reads in (bar1(ti), bar2(ti)).
    // g-region: writes in (bar1(ti), bar2(ti)); reads in (bar2(ti), bar1(ti+1)).
    // Disjoint windows -> single-buffered is race-free.
    __shared__ f32x4 lds_f[2][64];
    __shared__ f32x4 lds_g[4][64];

    // ---- weight A-frags (both waves load all; setup-only cost) ----
    s16x8 W1A[4], W2P[2], WihP[3], WhhA[3], WoutA;
    #pragma unroll
    for (int c = 0; c < 4; ++c) W1A[c] = load_pair(W1, 16, 16 * c, 0, 50, 16, lane);
    #pragma unroll
    for (int c = 0; c < 2; ++c) W2P[c] = load_plain32(W2, 50, 0, 32 * c, 16, 50, lane);
    #pragma unroll
    for (int m = 0; m < 3; ++m) WihP[m] = load_plain32(Wih, 32, 16 * m, 0, 48, 32, lane);
    #pragma unroll
    for (int m = 0; m < 3; ++m) WhhA[m] = load_pair(Whh, 16, 16 * m, 0, 48, 16, lane);
    WoutA = load_pair(Wout, 16, 0, 0, 1, 16, lane);   // row 0 only

    // ---- bias C-frags ----
    f32x4 b1f[4], brzf[2], b2f, bxnf, bhnf, boutC;
    #pragma unroll
    for (int c = 0; c < 4; ++c)
        #pragma unroll
        for (int i = 0; i < 4; ++i) {
            int rr = 16 * c + 4 * g + i;
            b1f[c][i] = (rr < 50) ? b1[rr] : 0.0f;
        }
    #pragma unroll
    for (int i = 0; i < 4; ++i) {
        b2f[i]  = b2[4 * g + i];
        brzf[0][i] = bih[4 * g + i]      + bhh[4 * g + i];
        brzf[1][i] = bih[16 + 4 * g + i] + bhh[16 + 4 * g + i];
        bxnf[i] = bih[32 + 4 * g + i];
        bhnf[i] = bhh[32 + 4 * g + i];
        boutC[i] = 0.0f;
    }
    if (g == 0) boutC[0] = bout[0];

    const f32x4 zero4 = {0.0f, 0.0f, 0.0f, 0.0f};

    // ---- state (replicated in both waves; updates are IEEE-commutative
    //      so both copies stay bit-identical) ----
    f32x4 h = zero4;
    s16x8 hb = make_hi(h);

    // ---- x pipeline + prologue x-side MFMAs (split by wave) ----
    const float* xbase = x + ((size_t)(ebase + col) << 5) + 4 * g;
    f32x4 xa = *(const f32x4*)(xbase);
    f32x4 xb = *(const f32x4*)(xbase + 16);
    s16x8 xB = pack2(xa, xb);
    f32x4 gr_x = zero4, gz_x = zero4, gxn = zero4;
    if (w == 0) {
        gr_x = MFMA(WihP[0], xB, brzf[0]);
        gz_x = MFMA(WihP[1], xB, brzf[1]);
    } else {
        gxn = MFMA(WihP[2], xB, bxnf);
    }

    float tcur = t[0];
    float tn   = t[1];

    for (int ti = 0; ti < T_STEPS - 1; ++ti) {
        // prefetch next x (both waves, same addrs -> L1 broadcast)
        const float* xnxt = xbase + ((size_t)(ti + 1) * BATCH << 5);
        const f32x4 xa_n = *(const f32x4*)(xnxt);
        const f32x4 xb_n = *(const f32x4*)(xnxt + 16);
        const int ti2 = (ti + 2 < T_STEPS) ? (ti + 2) : (T_STEPS - 1);
        const float tnn = t[ti2];

        const float dt = tn - tcur;
        tcur = tn;
        tn = tnn;

        // ---- ODE phase: forward Euler, split across waves ----
        // w0: W1 rows 0-31 -> poly -> W2 K-chunk 0-31 partial (+b2)
        // w1: W1 rows 32-63 -> poly -> W2 K-chunk 32-63 partial
        f32x4 fp;
        if (w == 0) {
            f32x4 y0 = MFMA(W1A[0], hb, b1f[0]);
            f32x4 y1 = MFMA(W1A[1], hb, b1f[1]);
            f32x4 t0, t1;
            #pragma unroll
            for (int i = 0; i < 4; ++i) t0[i] = poly_tanh(y0[i]);
            #pragma unroll
            for (int i = 0; i < 4; ++i) t1[i] = poly_tanh(y1[i]);
            fp = MFMA(W2P[0], pack2(t0, t1), b2f);
        } else {
            f32x4 y2 = MFMA(W1A[2], hb, b1f[2]);
            f32x4 y3 = MFMA(W1A[3], hb, b1f[3]);   // rows 50-63 zero -> poly(0)=0
            f32x4 t2, t3;
            #pragma unroll
            for (int i = 0; i < 4; ++i) t2[i] = poly_tanh(y2[i]);
            #pragma unroll
            for (int i = 0; i < 4; ++i) t3[i] = poly_tanh(y3[i]);
            fp = MFMA(W2P[1], pack2(t2, t3), zero4);
        }
        lds_f[w][lane] = fp;
        __syncthreads();                       // barrier 1
        const f32x4 fo = lds_f[w ^ 1][lane];
        h += dt * (fp + fo);

        // ---- GRU phase: h-side MFMAs split across waves ----
        const s16x8 hh = make_hi(h);
        f32x4 grr, gzz, gxt, ght;
        if (w == 0) {
            grr = MFMA(WhhA[0], hh, gr_x);
            gzz = MFMA(WhhA[1], hh, gz_x);
            lds_g[0][lane] = grr;
            lds_g[1][lane] = gzz;
        } else {
            ght = MFMA(WhhA[2], hh, bhnf);
            lds_g[2][lane] = gxn;
            lds_g[3][lane] = ght;
        }
        __syncthreads();                       // barrier 2
        if (w == 0) {
            gxt = lds_g[2][lane];
            ght = lds_g[3][lane];
        } else {
            grr = lds_g[0][lane];
            gzz = lds_g[1][lane];
            gxt = gxn;                         // FIX: w1 uses its local gxn
        }

        // gate nonlinearities + h update (redundant in both waves)
        f32x4 hnew;
        #pragma unroll
        for (int i = 0; i < 4; ++i) {
            const float r = fast_sigmoid(grr[i]);
            const float z = fast_sigmoid(gzz[i]);
            const float n = fast_tanh(gxt[i] + r * ght[i]);
            hnew[i] = n + z * (h[i] - n);
        }
        h = hnew;

        // ---- tail: next-step x-side MFMAs + out projection, split ----
        xB = pack2(xa_n, xb_n);
        hb = make_hi(h);
        if (w == 0) {
            gr_x = MFMA(WihP[0], xB, brzf[0]);
            gz_x = MFMA(WihP[1], xB, brzf[1]);
        } else {
            gxn = MFMA(WihP[2], xB, bxnf);
            f32x4 od = MFMA(WoutA, hb, boutC);
            if (lane < 16) out[(size_t)ti * BATCH + ebase + lane] = od[0];
        }
    }
}

extern "C" void kernel_launch(void* const* d_in, const int* in_sizes, int n_in,
                              void* d_out, int out_size, void* d_ws, size_t ws_size,
                              hipStream_t stream) {
    const float* x    = (const float*)d_in[0];
    const float* t    = (const float*)d_in[1];
    const float* W1   = (const float*)d_in[2];
    const float* b1   = (const float*)d_in[3];
    const float* W2   = (const float*)d_in[4];
    const float* b2   = (const float*)d_in[5];
    const float* Wih  = (const float*)d_in[6];
    const float* bih  = (const float*)d_in[7];
    const float* Whh  = (const float*)d_in[8];
    const float* bhh  = (const float*)d_in[9];
    const float* Wout = (const float*)d_in[10];
    const float* bout = (const float*)d_in[11];
    float* out = (float*)d_out;

    dim3 grid(BATCH / 16), block(128);
    hipLaunchKernelGGL(odernn_mfma2, grid, block, 0, stream,
                       x, t, W1, b1, W2, b2, Wih, bih, Whh, bhh, Wout, bout, out);
}

// Round 15
// 320.440 us; speedup vs baseline: 1.3076x; 1.2340x over previous
//
#include <hip/hip_runtime.h>

#define T_STEPS 500
#define BATCH   4096

typedef float f32x4 __attribute__((ext_vector_type(4)));
typedef short s16x8 __attribute__((ext_vector_type(8)));

__device__ __forceinline__ unsigned short bf16_rne(float f) {
    union { float f; unsigned u; } c; c.f = f;
    unsigned u = c.u;
    return (unsigned short)((u + 0x7FFFu + ((u >> 16) & 1u)) >> 16);
}
__device__ __forceinline__ float bf16_tof(unsigned short h) {
    union { unsigned u; float f; } c; c.u = ((unsigned)h) << 16;
    return c.f;
}

// B-frag [v|v]: duplicated into both K-16 halves (for compensated K=16 ops)
__device__ __forceinline__ s16x8 make_hi(f32x4 v) {
    unsigned p01, p23;
    asm("v_cvt_pk_bf16_f32 %0, %1, %2" : "=v"(p01) : "v"(v[0]), "v"(v[1]));
    asm("v_cvt_pk_bf16_f32 %0, %1, %2" : "=v"(p23) : "v"(v[2]), "v"(v[3]));
    union { unsigned u[4]; s16x8 s; } r;
    r.u[0] = p01; r.u[1] = p23; r.u[2] = p01; r.u[3] = p23;
    return r.s;
}

// B-frag [a|b]: two different 16-wide K-halves (plain K=32 ops)
__device__ __forceinline__ s16x8 pack2(f32x4 a, f32x4 b) {
    unsigned p01, p23, q01, q23;
    asm("v_cvt_pk_bf16_f32 %0, %1, %2" : "=v"(p01) : "v"(a[0]), "v"(a[1]));
    asm("v_cvt_pk_bf16_f32 %0, %1, %2" : "=v"(p23) : "v"(a[2]), "v"(a[3]));
    asm("v_cvt_pk_bf16_f32 %0, %1, %2" : "=v"(q01) : "v"(b[0]), "v"(b[1]));
    asm("v_cvt_pk_bf16_f32 %0, %1, %2" : "=v"(q23) : "v"(b[2]), "v"(b[3]));
    union { unsigned u[4]; s16x8 s; } r;
    r.u[0] = p01; r.u[1] = p23; r.u[2] = q01; r.u[3] = q23;
    return r.s;
}

// Compensated A-frag [Whi|Wlo] over one K-16 chunk (use with B=[a|a]).
__device__ __forceinline__ s16x8 load_pair(const float* __restrict__ W, int ld,
                                           int m0, int k0, int M, int K, int lane) {
    const int m = m0 + (lane & 15);
    const int g = lane >> 4;
    s16x8 r;
    #pragma unroll
    for (int j = 0; j < 4; ++j) {
        const int k = k0 + 4 * g + j;
        const float w = (m < M && k < K) ? W[m * ld + k] : 0.0f;
        const unsigned short hi = bf16_rne(w);
        const unsigned short lo = bf16_rne(w - bf16_tof(hi));
        r[j]     = (short)hi;
        r[j + 4] = (short)lo;
    }
    return r;
}

// Plain bf16 A-frag over a K-32 window (use with pack2 B-frags).
// Slot map mirrors pack2: j<4 -> k0+4g+j ; j>=4 -> k0+16+4g+(j-4).
__device__ __forceinline__ s16x8 load_plain32(const float* __restrict__ W, int ld,
                                              int m0, int k0, int M, int K, int lane) {
    const int m = m0 + (lane & 15);
    const int g = lane >> 4;
    s16x8 r;
    #pragma unroll
    for (int j = 0; j < 8; ++j) {
        const int k = k0 + ((j < 4) ? (4 * g + j) : (16 + 4 * g + (j - 4)));
        const float w = (m < M && k < K) ? W[m * ld + k] : 0.0f;
        r[j] = (short)bf16_rne(w);
    }
    return r;
}

// ODE tanh: odd deg-7 fit on [0,1.5] (|err|<9e-4; args are 0.1-scale dot
// products; error is dt-scaled in h). poly(0)==0 exactly.
__device__ __forceinline__ float poly_tanh(float x) {
    const float u = x * x;
    float p = fmaf(u, -0.0136472f, 0.0941244f);
    p = fmaf(u, p, -0.3183021f);
    p = fmaf(u, p, 0.9985576f);
    return x * p;
}

// GRU gates: wide-range, trans-based (only 12 values/step).
__device__ __forceinline__ float fast_tanh(float x) {
    float e = __builtin_amdgcn_exp2f(2.8853900817779268f * x);
    return fmaf(-2.0f, __builtin_amdgcn_rcpf(e + 1.0f), 1.0f);
}
__device__ __forceinline__ float fast_sigmoid(float x) {
    float e = __builtin_amdgcn_exp2f(-1.4426950408889634f * x);
    return __builtin_amdgcn_rcpf(1.0f + e);
}

#define MFMA(a, b, c) __builtin_amdgcn_mfma_f32_16x16x32_bf16((a), (b), (c), 0, 0, 0)

__global__ __launch_bounds__(64) void odernn_mfma(
    const float* __restrict__ x,    // [T, B, 32]
    const float* __restrict__ t,    // [T]
    const float* __restrict__ W1, const float* __restrict__ b1,   // [50,16],[50]
    const float* __restrict__ W2, const float* __restrict__ b2,   // [16,50],[16]
    const float* __restrict__ Wih, const float* __restrict__ bih, // [48,32],[48]
    const float* __restrict__ Whh, const float* __restrict__ bhh, // [48,16],[48]
    const float* __restrict__ Wout, const float* __restrict__ bout,
    float* __restrict__ out)        // [T-1, B, 1]
{
    const int lane  = threadIdx.x;
    const int g     = lane >> 4;
    const int col   = lane & 15;
    const int ebase = blockIdx.x * 16;

    // ---- weight A-frags ----
    s16x8 W1A[4], W2P[2], WihP[3], WhhA[3], WoutA;
    #pragma unroll
    for (int c = 0; c < 4; ++c) W1A[c] = load_pair(W1, 16, 16 * c, 0, 50, 16, lane);
    #pragma unroll
    for (int c = 0; c < 2; ++c) W2P[c] = load_plain32(W2, 50, 0, 32 * c, 16, 50, lane);
    #pragma unroll
    for (int m = 0; m < 3; ++m) WihP[m] = load_plain32(Wih, 32, 16 * m, 0, 48, 32, lane);
    #pragma unroll
    for (int m = 0; m < 3; ++m) WhhA[m] = load_pair(Whh, 16, 16 * m, 0, 48, 16, lane);
    WoutA = load_pair(Wout, 16, 0, 0, 1, 16, lane);   // row 0 only

    // ---- bias C-frags (f32, row = 4g + i within tile) ----
    f32x4 b1f[4], brzf[2], b2f, bxnf, bhnf, boutC;
    #pragma unroll
    for (int c = 0; c < 4; ++c)
        #pragma unroll
        for (int i = 0; i < 4; ++i) {
            int rr = 16 * c + 4 * g + i;
            b1f[c][i] = (rr < 50) ? b1[rr] : 0.0f;
        }
    #pragma unroll
    for (int i = 0; i < 4; ++i) {
        b2f[i]  = b2[4 * g + i];
        brzf[0][i] = bih[4 * g + i]      + bhh[4 * g + i];
        brzf[1][i] = bih[16 + 4 * g + i] + bhh[16 + 4 * g + i];
        bxnf[i] = bih[32 + 4 * g + i];
        bhnf[i] = bhh[32 + 4 * g + i];
        boutC[i] = 0.0f;
    }
    if (g == 0) boutC[0] = bout[0];

    // ---- state ----
    f32x4 h = {0.0f, 0.0f, 0.0f, 0.0f};
    s16x8 hb = make_hi(h);                 // carried bf16 frag of h

    // ---- pipelined loads: x one step ahead, t two steps ahead ----
    const float* xbase = x + ((size_t)(ebase + col) << 5) + 4 * g;
    f32x4 xa_cur = *(const f32x4*)(xbase);
    f32x4 xb_cur = *(const f32x4*)(xbase + 16);
    float tcur = t[0];
    float tn   = t[1];

    for (int ti = 0; ti < T_STEPS - 1; ++ti) {
        const float* xnxt = xbase + ((size_t)(ti + 1) * BATCH << 5);
        const f32x4 xa_n = *(const f32x4*)(xnxt);
        const f32x4 xb_n = *(const f32x4*)(xnxt + 16);
        const int ti2 = (ti + 2 < T_STEPS) ? (ti + 2) : (T_STEPS - 1);
        const float tnn = t[ti2];

        const float dt = tn - tcur;
        tcur = tn;
        tn = tnn;

        // ---- x-side GRU MFMAs first (independent of ODE) ----
        const s16x8 xB = pack2(xa_cur, xb_cur);       // [x0..15 | x16..31]
        f32x4 gr_x = MFMA(WihP[0], xB, brzf[0]);
        f32x4 gz_x = MFMA(WihP[1], xB, brzf[1]);
        f32x4 gxn  = MFMA(WihP[2], xB, bxnf);

        // ---- ODE: forward Euler over the full interval.
        // LTE = dt^2/2*|Jf| ~ 1.5e-5/step; GRU z-gate contraction (mult ~0.65)
        // -> steady-state added error ~4e-5, far below bf16-rounding floor.
        f32x4 y0 = MFMA(W1A[0], hb, b1f[0]);
        f32x4 y1 = MFMA(W1A[1], hb, b1f[1]);
        f32x4 y2 = MFMA(W1A[2], hb, b1f[2]);
        f32x4 y3 = MFMA(W1A[3], hb, b1f[3]);   // rows 50-63: zero W,b -> y=0, poly(0)=0
        f32x4 t0, t1, t2, t3;
        #pragma unroll
        for (int i = 0; i < 4; ++i) t0[i] = poly_tanh(y0[i]);
        #pragma unroll
        for (int i = 0; i < 4; ++i) t1[i] = poly_tanh(y1[i]);
        #pragma unroll
        for (int i = 0; i < 4; ++i) t2[i] = poly_tanh(y2[i]);
        #pragma unroll
        for (int i = 0; i < 4; ++i) t3[i] = poly_tanh(y3[i]);
        f32x4 f = MFMA(W2P[0], pack2(t0, t1), b2f);
        f = MFMA(W2P[1], pack2(t2, t3), f);
        h += dt * f;

        // ---- GRU h-side: 3 MFMAs on the post-ODE critical path ----
        const s16x8 hh = make_hi(h);
        const f32x4 gr = MFMA(WhhA[0], hh, gr_x);
        const f32x4 gz = MFMA(WhhA[1], hh, gz_x);
        const f32x4 ghn = MFMA(WhhA[2], hh, bhnf);

        f32x4 hnew;
        #pragma unroll
        for (int i = 0; i < 4; ++i) {
            const float r = fast_sigmoid(gr[i]);
            const float z = fast_sigmoid(gz[i]);
            const float n = fast_tanh(gxn[i] + r * ghn[i]);
            hnew[i] = n + z * (h[i] - n);
        }
        h = hnew;

        // ---- out projection via MFMA; hb also feeds next step's ODE ----
        hb = make_hi(h);
        f32x4 od = MFMA(WoutA, hb, boutC);
        if (lane < 16) out[(size_t)ti * BATCH + ebase + lane] = od[0];

        xa_cur = xa_n;
        xb_cur = xb_n;
    }
}

extern "C" void kernel_launch(void* const* d_in, const int* in_sizes, int n_in,
                              void* d_out, int out_size, void* d_ws, size_t ws_size,
                              hipStream_t stream) {
    const float* x    = (const float*)d_in[0];
    const float* t    = (const float*)d_in[1];
    const float* W1   = (const float*)d_in[2];
    const float* b1   = (const float*)d_in[3];
    const float* W2   = (const float*)d_in[4];
    const float* b2   = (const float*)d_in[5];
    const float* Wih  = (const float*)d_in[6];
    const float* bih  = (const float*)d_in[7];
    const float* Whh  = (const float*)d_in[8];
    const float* bhh  = (const float*)d_in[9];
    const float* Wout = (const float*)d_in[10];
    const float* bout = (const float*)d_in[11];
    float* out = (float*)d_out;

    dim3 grid(BATCH / 16), block(64);
    hipLaunchKernelGGL(odernn_mfma, grid, block, 0, stream,
                       x, t, W1, b1, W2, b2, Wih, bih, Whh, bhh, Wout, bout, out);
}